// Round 6
// baseline (100.025 us; speedup 1.0000x reference)
//
#include <hip/hip_runtime.h>
#include <hip/hip_bf16.h>

#define N_NODES 50000
#define DEG 16
#define IN_DIM 256
#define OUT_DIM 64
#define HEADS 4
#define C_DIM 256   /* HEADS*OUT_DIM */
#define SLOPE 0.01f

typedef __attribute__((ext_vector_type(8))) short short8;
typedef __attribute__((ext_vector_type(4))) float f32x4;

static __device__ __forceinline__ float bf2f(unsigned int u16) {
    union { unsigned int i; float f; } v; v.i = (u16 & 0xffffu) << 16; return v.f;
}
static __device__ __forceinline__ unsigned short f2bf(float f) {
    union { float f; unsigned int i; } v; v.f = f;
    unsigned int u = v.i;
    return (unsigned short)((u + 0x7fffu + ((u >> 16) & 1u)) >> 16);  // RNE
}
static __device__ __forceinline__ unsigned int cvt_pk_bf16(float lo, float hi) {
    unsigned int w;
    asm("v_cvt_pk_bf16_f32 %0, %1, %2" : "=v"(w) : "v"(lo), "v"(hi));
    return w;
}
static __device__ __forceinline__ short8 pack8(float4 a0, float4 a1) {
    union { unsigned int w[4]; short8 s; } u;
    u.w[0] = cvt_pk_bf16(a0.x, a0.y);
    u.w[1] = cvt_pk_bf16(a0.z, a0.w);
    u.w[2] = cvt_pk_bf16(a1.x, a1.y);
    u.w[3] = cvt_pk_bf16(a1.z, a1.w);
    return u.s;
}

// ---------------- Kernel 0: pack W[h][k][d] (f32) -> Bp slice-major:
// Bp[(k>>6)*16384 + c*64 + (k&63)] (bf16), c = h*64+d.  (slice = 64 k's)
__global__ __launch_bounds__(256) void k_prep(const float* __restrict__ W,
                                              unsigned short* __restrict__ Bp) {
    const int c = blockIdx.x;           // 0..255
    const int k = threadIdx.x;          // 0..255
    const int hh = c >> 6, d = c & 63;
    Bp[(k >> 6) * 16384 + c * 64 + (k & 63)] =
        f2bf(W[hh * (IN_DIM * OUT_DIM) + k * OUT_DIM + d]);
}

// ---------------- Kernel 1: z = h @ Wcat via bf16 MFMA, LDS-staged B. (unchanged, r5)
__global__ __launch_bounds__(256) void k_proj(const float* __restrict__ h,
                                              const unsigned short* __restrict__ Bp,
                                              const float* __restrict__ a_src,
                                              const float* __restrict__ a_dst,
                                              unsigned short* __restrict__ z,
                                              float* __restrict__ es,
                                              float* __restrict__ ed) {
    __shared__ unsigned char Bs[2][32768];
    const int tid  = threadIdx.x;
    const int lane = tid & 63;
    const int wave = tid >> 6;
    const int wb   = blockIdx.x * 64 + wave * 16;
    const int n    = lane & 15;        // tile col / A row
    const int g    = lane >> 4;        // k-group

    int arow = wb + n; if (arow >= N_NODES) arow = N_NODES - 1;
    const float* hrow = h + (size_t)arow * IN_DIM;

    const int lbase = (n * 64 + g * 16) ^ ((n & 7) << 4);

    f32x4 acc[16];
    #pragma unroll
    for (int ct = 0; ct < 16; ct++) acc[ct] = (f32x4){0.f, 0.f, 0.f, 0.f};

    uint4  breg[8];
    float4 areg[4];
    short8 af0, af1;

    #pragma unroll
    for (int i = 0; i < 8; i++)
        breg[i] = *(const uint4*)((const char*)Bp + (size_t)(i * 256 + tid) * 16);
    #pragma unroll
    for (int ks2 = 0; ks2 < 2; ks2++) {
        areg[ks2 * 2]     = *(const float4*)(hrow + ks2 * 32 + g * 8);
        areg[ks2 * 2 + 1] = *(const float4*)(hrow + ks2 * 32 + g * 8 + 4);
    }
    #pragma unroll
    for (int i = 0; i < 8; i++) {
        const int L = i * 256 + tid;
        const int c = L >> 3, gg = L & 3, kk2 = (L >> 2) & 1;
        int woff = (kk2 << 14) + c * 64 + (gg << 4);
        woff ^= ((c & 7) << 4);
        *(uint4*)(&Bs[0][woff]) = breg[i];
    }
    af0 = pack8(areg[0], areg[1]);
    af1 = pack8(areg[2], areg[3]);
    __syncthreads();

    #pragma unroll
    for (int s = 0; s < 4; s++) {
        const int buf = s & 1;
        if (s < 3) {
            const char* bsrc = (const char*)Bp + (size_t)(s + 1) * 32768;
            #pragma unroll
            for (int i = 0; i < 8; i++)
                breg[i] = *(const uint4*)(bsrc + (size_t)(i * 256 + tid) * 16);
            #pragma unroll
            for (int ks2 = 0; ks2 < 2; ks2++) {
                areg[ks2 * 2]     = *(const float4*)(hrow + (s + 1) * 64 + ks2 * 32 + g * 8);
                areg[ks2 * 2 + 1] = *(const float4*)(hrow + (s + 1) * 64 + ks2 * 32 + g * 8 + 4);
            }
        }
        #pragma unroll
        for (int ct = 0; ct < 16; ct++) {
            union { uint4 u; short8 s8; } b0, b1;
            b0.u = *(const uint4*)(&Bs[buf][ct * 1024 + lbase]);
            b1.u = *(const uint4*)(&Bs[buf][16384 + ct * 1024 + lbase]);
            acc[ct] = __builtin_amdgcn_mfma_f32_16x16x32_bf16(af0, b0.s8, acc[ct], 0, 0, 0);
            acc[ct] = __builtin_amdgcn_mfma_f32_16x16x32_bf16(af1, b1.s8, acc[ct], 0, 0, 0);
        }
        if (s < 3) {
            #pragma unroll
            for (int i = 0; i < 8; i++) {
                const int L = i * 256 + tid;
                const int c = L >> 3, gg = L & 3, kk2 = (L >> 2) & 1;
                int woff = (kk2 << 14) + c * 64 + (gg << 4);
                woff ^= ((c & 7) << 4);
                *(uint4*)(&Bs[buf ^ 1][woff]) = breg[i];
            }
            af0 = pack8(areg[0], areg[1]);
            af1 = pack8(areg[2], areg[3]);
            __syncthreads();
        }
    }

    const int g2 = lane >> 4;
    #pragma unroll
    for (int ct = 0; ct < 16; ct++) {
        #pragma unroll
        for (int r = 0; r < 4; r++) {
            const int m = wb + g2 * 4 + r;
            if (m < N_NODES) z[(size_t)m * C_DIM + ct * 16 + n] = f2bf(acc[ct][r]);
        }
    }

    float keep_s = 0.f, keep_d = 0.f;
    #pragma unroll
    for (int hh = 0; hh < 4; hh++) {
        #pragma unroll
        for (int r = 0; r < 4; r++) {
            float vs = 0.f, vd = 0.f;
            #pragma unroll
            for (int q = 0; q < 4; q++) {
                const int ct = hh * 4 + q;
                const int c  = ct * 16 + n;
                vs = fmaf(acc[ct][r], a_src[c], vs);
                vd = fmaf(acc[ct][r], a_dst[c], vd);
            }
            #pragma unroll
            for (int o = 1; o < 16; o <<= 1) {
                vs += __shfl_xor(vs, o, 64);
                vd += __shfl_xor(vd, o, 64);
            }
            if (n == (hh << 2 | r)) { keep_s = vs; keep_d = vd; }
        }
    }
    {
        const int m = wb + g2 * 4 + (n & 3);
        const int hh = n >> 2;
        if (m < N_NODES) {
            es[m * 4 + hh] = keep_s;
            ed[m * 4 + hh] = keep_d;
        }
    }
}

// ---------------- Kernel 2: softmax over 16 in-edges + weighted gather-sum.
// v2: batch-issued gathers. Lane loads 16B (uint4); half-wave (lane>>5) picks
// row parity; 8 load instrs per node, ALL in flight before first use.
// Lane owns cols q*8..q*8+7 (q = lane&31) for its half's 8 edges; halves
// combine via shfl_xor(32); coalesced 1KB row store.
__global__ __launch_bounds__(256) void k_attn(const unsigned short* __restrict__ z,
                                              const float* __restrict__ es,
                                              const float* __restrict__ ed,
                                              const int* __restrict__ src,
                                              float* __restrict__ out) {
    const int lane = threadIdx.x & 63;
    const int n = blockIdx.x * 4 + (threadIdx.x >> 6);
    const int j16 = lane & 15;
    const int h4 = lane >> 4;
    const int half = lane >> 5;          // 0/1: row parity
    const int q    = lane & 31;          // col-chunk: cols q*8 .. q*8+7
    const int headq = q >> 3;            // head of those cols

    // edge src ids (lane j16 holds edge j16's src)
    const int s = src[n * DEG + j16];

    // ---- issue ALL z-row gathers first (8 x 16B per lane, rows 2t+half)
    uint4 rows[8];
    #pragma unroll
    for (int t = 0; t < 8; t++) {
        const int sj = __shfl(s, 2 * t + half, 64);
        rows[t] = *(const uint4*)(z + (size_t)sj * C_DIM + q * 8);
    }

    // ---- softmax (runs while gathers are in flight)
    float e = es[s * 4 + h4] + ed[n * 4 + h4];
    e = (e >= 0.f) ? e : SLOPE * e;
    float m = e;
    #pragma unroll
    for (int o = 1; o < 16; o <<= 1) m = fmaxf(m, __shfl_xor(m, o, 64));
    const float ex = __expf(e - m);
    float sum = ex;
    #pragma unroll
    for (int o = 1; o < 16; o <<= 1) sum += __shfl_xor(sum, o, 64);
    const float alpha = ex / sum;   // alpha for (head h4, edge j16)

    // ---- accumulate: lane's 8 cols over its half's 8 edges
    float acc[8];
    #pragma unroll
    for (int c = 0; c < 8; c++) acc[c] = 0.f;
    #pragma unroll
    for (int t = 0; t < 8; t++) {
        const float al = __shfl(alpha, headq * 16 + 2 * t + half, 64);
        const uint4 v = rows[t];
        acc[0] = fmaf(al, bf2f(v.x), acc[0]);
        acc[1] = fmaf(al, bf2f(v.x >> 16), acc[1]);
        acc[2] = fmaf(al, bf2f(v.y), acc[2]);
        acc[3] = fmaf(al, bf2f(v.y >> 16), acc[3]);
        acc[4] = fmaf(al, bf2f(v.z), acc[4]);
        acc[5] = fmaf(al, bf2f(v.z >> 16), acc[5]);
        acc[6] = fmaf(al, bf2f(v.w), acc[6]);
        acc[7] = fmaf(al, bf2f(v.w >> 16), acc[7]);
    }
    // combine halves (each half summed 8 of the 16 edges)
    #pragma unroll
    for (int c = 0; c < 8; c++) acc[c] += __shfl_xor(acc[c], 32, 64);

    // ---- store: half 0 writes cols q*8..+3, half 1 writes q*8+4..+7
    const float4 wv = half ? make_float4(acc[4], acc[5], acc[6], acc[7])
                           : make_float4(acc[0], acc[1], acc[2], acc[3]);
    *(float4*)(out + (size_t)n * C_DIM + q * 8 + half * 4) = wv;
}

extern "C" void kernel_launch(void* const* d_in, const int* in_sizes, int n_in,
                              void* d_out, int out_size, void* d_ws, size_t ws_size,
                              hipStream_t stream) {
    const float* h     = (const float*)d_in[0];
    const float* W     = (const float*)d_in[1];
    const float* a_src = (const float*)d_in[2];
    const float* a_dst = (const float*)d_in[3];
    const int*   src   = (const int*)d_in[4];
    // d_in[5] (dst) is repeat(arange(N), DEG) -> implicit in indexing.

    unsigned short* z  = (unsigned short*)d_ws;                       // [N][256] bf16
    float* es = (float*)((char*)d_ws + (size_t)N_NODES * C_DIM * 2);  // [N][4] f32
    float* ed = es + (size_t)N_NODES * HEADS;                         // [N][4] f32
    unsigned short* Bp = (unsigned short*)((char*)d_ws +
                         (size_t)N_NODES * C_DIM * 2 +
                         (size_t)N_NODES * HEADS * 4 * 2);            // [4][256][64] bf16
    float* out = (float*)d_out;

    hipLaunchKernelGGL(k_prep, dim3(C_DIM),               dim3(IN_DIM), 0, stream, W, Bp);
    hipLaunchKernelGGL(k_proj, dim3((N_NODES + 63) / 64), dim3(256),    0, stream,
                       h, Bp, a_src, a_dst, z, es, ed);
    hipLaunchKernelGGL(k_attn, dim3(N_NODES / 4),         dim3(256),    0, stream,
                       z, es, ed, src, out);
}

// Round 8
// 98.820 us; speedup vs baseline: 1.0122x; 1.0122x over previous
//
#include <hip/hip_runtime.h>
#include <hip/hip_bf16.h>

#define N_NODES 50000
#define DEG 16
#define IN_DIM 256
#define OUT_DIM 64
#define HEADS 4
#define C_DIM 256   /* HEADS*OUT_DIM */
#define SLOPE 0.01f

typedef __attribute__((ext_vector_type(8))) short short8;
typedef __attribute__((ext_vector_type(4))) float f32x4;

static __device__ __forceinline__ float bf2f(unsigned int u16) {
    union { unsigned int i; float f; } v; v.i = (u16 & 0xffffu) << 16; return v.f;
}
static __device__ __forceinline__ unsigned short f2bf(float f) {
    union { float f; unsigned int i; } v; v.f = f;
    unsigned int u = v.i;
    return (unsigned short)((u + 0x7fffu + ((u >> 16) & 1u)) >> 16);  // RNE
}
static __device__ __forceinline__ unsigned int cvt_pk_bf16(float lo, float hi) {
    unsigned int w;
    asm("v_cvt_pk_bf16_f32 %0, %1, %2" : "=v"(w) : "v"(lo), "v"(hi));
    return w;
}
static __device__ __forceinline__ short8 pack8(float4 a0, float4 a1) {
    union { unsigned int w[4]; short8 s; } u;
    u.w[0] = cvt_pk_bf16(a0.x, a0.y);
    u.w[1] = cvt_pk_bf16(a0.z, a0.w);
    u.w[2] = cvt_pk_bf16(a1.x, a1.y);
    u.w[3] = cvt_pk_bf16(a1.z, a1.w);
    return u.s;
}

// ---------------- Kernel 0: pack W[h][k][d] (f32) -> Bp slice-major (unchanged, r5)
__global__ __launch_bounds__(256) void k_prep(const float* __restrict__ W,
                                              unsigned short* __restrict__ Bp) {
    const int c = blockIdx.x;           // 0..255
    const int k = threadIdx.x;          // 0..255
    const int hh = c >> 6, d = c & 63;
    Bp[(k >> 6) * 16384 + c * 64 + (k & 63)] =
        f2bf(W[hh * (IN_DIM * OUT_DIM) + k * OUT_DIM + d]);
}

// ---------------- Kernel 1: z = h @ Wcat via bf16 MFMA, LDS-staged B. (unchanged, r5)
__global__ __launch_bounds__(256) void k_proj(const float* __restrict__ h,
                                              const unsigned short* __restrict__ Bp,
                                              const float* __restrict__ a_src,
                                              const float* __restrict__ a_dst,
                                              unsigned short* __restrict__ z,
                                              float* __restrict__ es,
                                              float* __restrict__ ed) {
    __shared__ unsigned char Bs[2][32768];
    const int tid  = threadIdx.x;
    const int lane = tid & 63;
    const int wave = tid >> 6;
    const int wb   = blockIdx.x * 64 + wave * 16;
    const int n    = lane & 15;        // tile col / A row
    const int g    = lane >> 4;        // k-group

    int arow = wb + n; if (arow >= N_NODES) arow = N_NODES - 1;
    const float* hrow = h + (size_t)arow * IN_DIM;

    const int lbase = (n * 64 + g * 16) ^ ((n & 7) << 4);

    f32x4 acc[16];
    #pragma unroll
    for (int ct = 0; ct < 16; ct++) acc[ct] = (f32x4){0.f, 0.f, 0.f, 0.f};

    uint4  breg[8];
    float4 areg[4];
    short8 af0, af1;

    #pragma unroll
    for (int i = 0; i < 8; i++)
        breg[i] = *(const uint4*)((const char*)Bp + (size_t)(i * 256 + tid) * 16);
    #pragma unroll
    for (int ks2 = 0; ks2 < 2; ks2++) {
        areg[ks2 * 2]     = *(const float4*)(hrow + ks2 * 32 + g * 8);
        areg[ks2 * 2 + 1] = *(const float4*)(hrow + ks2 * 32 + g * 8 + 4);
    }
    #pragma unroll
    for (int i = 0; i < 8; i++) {
        const int L = i * 256 + tid;
        const int c = L >> 3, gg = L & 3, kk2 = (L >> 2) & 1;
        int woff = (kk2 << 14) + c * 64 + (gg << 4);
        woff ^= ((c & 7) << 4);
        *(uint4*)(&Bs[0][woff]) = breg[i];
    }
    af0 = pack8(areg[0], areg[1]);
    af1 = pack8(areg[2], areg[3]);
    __syncthreads();

    #pragma unroll
    for (int s = 0; s < 4; s++) {
        const int buf = s & 1;
        if (s < 3) {
            const char* bsrc = (const char*)Bp + (size_t)(s + 1) * 32768;
            #pragma unroll
            for (int i = 0; i < 8; i++)
                breg[i] = *(const uint4*)(bsrc + (size_t)(i * 256 + tid) * 16);
            #pragma unroll
            for (int ks2 = 0; ks2 < 2; ks2++) {
                areg[ks2 * 2]     = *(const float4*)(hrow + (s + 1) * 64 + ks2 * 32 + g * 8);
                areg[ks2 * 2 + 1] = *(const float4*)(hrow + (s + 1) * 64 + ks2 * 32 + g * 8 + 4);
            }
        }
        #pragma unroll
        for (int ct = 0; ct < 16; ct++) {
            union { uint4 u; short8 s8; } b0, b1;
            b0.u = *(const uint4*)(&Bs[buf][ct * 1024 + lbase]);
            b1.u = *(const uint4*)(&Bs[buf][16384 + ct * 1024 + lbase]);
            acc[ct] = __builtin_amdgcn_mfma_f32_16x16x32_bf16(af0, b0.s8, acc[ct], 0, 0, 0);
            acc[ct] = __builtin_amdgcn_mfma_f32_16x16x32_bf16(af1, b1.s8, acc[ct], 0, 0, 0);
        }
        if (s < 3) {
            #pragma unroll
            for (int i = 0; i < 8; i++) {
                const int L = i * 256 + tid;
                const int c = L >> 3, gg = L & 3, kk2 = (L >> 2) & 1;
                int woff = (kk2 << 14) + c * 64 + (gg << 4);
                woff ^= ((c & 7) << 4);
                *(uint4*)(&Bs[buf ^ 1][woff]) = breg[i];
            }
            af0 = pack8(areg[0], areg[1]);
            af1 = pack8(areg[2], areg[3]);
            __syncthreads();
        }
    }

    const int g2 = lane >> 4;
    #pragma unroll
    for (int ct = 0; ct < 16; ct++) {
        #pragma unroll
        for (int r = 0; r < 4; r++) {
            const int m = wb + g2 * 4 + r;
            if (m < N_NODES) z[(size_t)m * C_DIM + ct * 16 + n] = f2bf(acc[ct][r]);
        }
    }

    float keep_s = 0.f, keep_d = 0.f;
    #pragma unroll
    for (int hh = 0; hh < 4; hh++) {
        #pragma unroll
        for (int r = 0; r < 4; r++) {
            float vs = 0.f, vd = 0.f;
            #pragma unroll
            for (int q = 0; q < 4; q++) {
                const int ct = hh * 4 + q;
                const int c  = ct * 16 + n;
                vs = fmaf(acc[ct][r], a_src[c], vs);
                vd = fmaf(acc[ct][r], a_dst[c], vd);
            }
            #pragma unroll
            for (int o = 1; o < 16; o <<= 1) {
                vs += __shfl_xor(vs, o, 64);
                vd += __shfl_xor(vd, o, 64);
            }
            if (n == (hh << 2 | r)) { keep_s = vs; keep_d = vd; }
        }
    }
    {
        const int m = wb + g2 * 4 + (n & 3);
        const int hh = n >> 2;
        if (m < N_NODES) {
            es[m * 4 + hh] = keep_s;
            ed[m * 4 + hh] = keep_d;
        }
    }
}

// ---------------- Kernel 2 v3: 2 nodes per wave -> 16 gather loads (256B/lane)
// all in flight before first use; softmax for both nodes hides latency.
__global__ __launch_bounds__(256) void k_attn(const unsigned short* __restrict__ z,
                                              const float* __restrict__ es,
                                              const float* __restrict__ ed,
                                              const int* __restrict__ src,
                                              float* __restrict__ out) {
    const int lane = threadIdx.x & 63;
    const int wave = threadIdx.x >> 6;
    const int base = blockIdx.x * 8 + wave * 2;   // nodes base, base+1
    const int j16 = lane & 15;
    const int h4 = lane >> 4;
    const int half = lane >> 5;          // 0/1: row parity within a node's 16 edges
    const int q    = lane & 31;          // col-chunk: cols q*8 .. q*8+7
    const int headq = q >> 3;            // head of those cols

    const int s0 = src[base * DEG + j16];
    const int s1 = src[(base + 1) * DEG + j16];

    // ---- issue ALL 16 row-gathers (2 nodes x 8) before any use
    uint4 rows0[8], rows1[8];
    #pragma unroll
    for (int t = 0; t < 8; t++) {
        const int sj = __shfl(s0, 2 * t + half, 64);
        rows0[t] = *(const uint4*)(z + (size_t)sj * C_DIM + q * 8);
    }
    #pragma unroll
    for (int t = 0; t < 8; t++) {
        const int sj = __shfl(s1, 2 * t + half, 64);
        rows1[t] = *(const uint4*)(z + (size_t)sj * C_DIM + q * 8);
    }

    // ---- softmax for both nodes (edge j16, head h4)
    float e0 = es[s0 * 4 + h4] + ed[base * 4 + h4];
    e0 = (e0 >= 0.f) ? e0 : SLOPE * e0;
    float e1 = es[s1 * 4 + h4] + ed[(base + 1) * 4 + h4];
    e1 = (e1 >= 0.f) ? e1 : SLOPE * e1;
    float m0 = e0, m1 = e1;
    #pragma unroll
    for (int o = 1; o < 16; o <<= 1) {
        m0 = fmaxf(m0, __shfl_xor(m0, o, 64));
        m1 = fmaxf(m1, __shfl_xor(m1, o, 64));
    }
    const float ex0 = __expf(e0 - m0);
    const float ex1 = __expf(e1 - m1);
    float sum0 = ex0, sum1 = ex1;
    #pragma unroll
    for (int o = 1; o < 16; o <<= 1) {
        sum0 += __shfl_xor(sum0, o, 64);
        sum1 += __shfl_xor(sum1, o, 64);
    }
    const float alpha0 = ex0 / sum0;
    const float alpha1 = ex1 / sum1;

    // ---- accumulate both nodes
    float acc0[8], acc1[8];
    #pragma unroll
    for (int c = 0; c < 8; c++) { acc0[c] = 0.f; acc1[c] = 0.f; }
    #pragma unroll
    for (int t = 0; t < 8; t++) {
        const float al0 = __shfl(alpha0, headq * 16 + 2 * t + half, 64);
        const uint4 v0 = rows0[t];
        acc0[0] = fmaf(al0, bf2f(v0.x), acc0[0]);
        acc0[1] = fmaf(al0, bf2f(v0.x >> 16), acc0[1]);
        acc0[2] = fmaf(al0, bf2f(v0.y), acc0[2]);
        acc0[3] = fmaf(al0, bf2f(v0.y >> 16), acc0[3]);
        acc0[4] = fmaf(al0, bf2f(v0.z), acc0[4]);
        acc0[5] = fmaf(al0, bf2f(v0.z >> 16), acc0[5]);
        acc0[6] = fmaf(al0, bf2f(v0.w), acc0[6]);
        acc0[7] = fmaf(al0, bf2f(v0.w >> 16), acc0[7]);
        const float al1 = __shfl(alpha1, headq * 16 + 2 * t + half, 64);
        const uint4 v1 = rows1[t];
        acc1[0] = fmaf(al1, bf2f(v1.x), acc1[0]);
        acc1[1] = fmaf(al1, bf2f(v1.x >> 16), acc1[1]);
        acc1[2] = fmaf(al1, bf2f(v1.y), acc1[2]);
        acc1[3] = fmaf(al1, bf2f(v1.y >> 16), acc1[3]);
        acc1[4] = fmaf(al1, bf2f(v1.z), acc1[4]);
        acc1[5] = fmaf(al1, bf2f(v1.z >> 16), acc1[5]);
        acc1[6] = fmaf(al1, bf2f(v1.w), acc1[6]);
        acc1[7] = fmaf(al1, bf2f(v1.w >> 16), acc1[7]);
    }
    #pragma unroll
    for (int c = 0; c < 8; c++) {
        acc0[c] += __shfl_xor(acc0[c], 32, 64);
        acc1[c] += __shfl_xor(acc1[c], 32, 64);
    }

    const float4 w0 = half ? make_float4(acc0[4], acc0[5], acc0[6], acc0[7])
                           : make_float4(acc0[0], acc0[1], acc0[2], acc0[3]);
    *(float4*)(out + (size_t)base * C_DIM + q * 8 + half * 4) = w0;
    const float4 w1 = half ? make_float4(acc1[4], acc1[5], acc1[6], acc1[7])
                           : make_float4(acc1[0], acc1[1], acc1[2], acc1[3]);
    *(float4*)(out + (size_t)(base + 1) * C_DIM + q * 8 + half * 4) = w1;
}

extern "C" void kernel_launch(void* const* d_in, const int* in_sizes, int n_in,
                              void* d_out, int out_size, void* d_ws, size_t ws_size,
                              hipStream_t stream) {
    const float* h     = (const float*)d_in[0];
    const float* W     = (const float*)d_in[1];
    const float* a_src = (const float*)d_in[2];
    const float* a_dst = (const float*)d_in[3];
    const int*   src   = (const int*)d_in[4];
    // d_in[5] (dst) is repeat(arange(N), DEG) -> implicit in indexing.

    unsigned short* z  = (unsigned short*)d_ws;                       // [N][256] bf16
    float* es = (float*)((char*)d_ws + (size_t)N_NODES * C_DIM * 2);  // [N][4] f32
    float* ed = es + (size_t)N_NODES * HEADS;                         // [N][4] f32
    unsigned short* Bp = (unsigned short*)((char*)d_ws +
                         (size_t)N_NODES * C_DIM * 2 +
                         (size_t)N_NODES * HEADS * 4 * 2);            // [4][256][64] bf16
    float* out = (float*)d_out;

    hipLaunchKernelGGL(k_prep, dim3(C_DIM),               dim3(IN_DIM), 0, stream, W, Bp);
    hipLaunchKernelGGL(k_proj, dim3((N_NODES + 63) / 64), dim3(256),    0, stream,
                       h, Bp, a_src, a_dst, z, es, ed);
    hipLaunchKernelGGL(k_attn, dim3(N_NODES / 8),         dim3(256),    0, stream,
                       z, es, ed, src, out);
}